// Round 14
// baseline (110.553 us; speedup 1.0000x reference)
//
#include <hip/hip_runtime.h>
#include <cstdint>
#include <cstddef>

#define BATCH 32
#define IMH 512
#define IMW 512
#define KMAX 256

// K1: register rolling-window NMS. Wave = 256 cols (4/lane), RPW output rows.
#define RPW 8
#define NBLKX 2
#define NBLKY 16
#define NBLK (NBLKX * NBLKY)   // 32 blocks/image
#define WCAP 512               // per-wave candidate cap = worst-case strict maxima in 256x8

#define TPB2 512               // tail threads (8 waves)

typedef unsigned long long u64;

__device__ __forceinline__ float sigmoidf_(float x) {
    return 1.0f / (1.0f + expf(-x));
}
__device__ __forceinline__ float scoref_(float r, float u) {
    const float sg = sigmoidf_(r);
    return sg * sg * (1.0f - 0.35f * sigmoidf_(u));
}

// ---------------------------------------------------------------------------
// K1: fused score + 3x3 NMS (register rolling window). Each WAVE owns a
// private 512-slot LDS region (appends = register counter + ballot prefix,
// zero atomics), bitonic-sorts it descending with NO barriers (same-wave LDS
// ops are in-order; volatile pins the compiler), then a 2-round pairwise
// top-256 merge tree (3 block barriers total) yields the block's sorted
// top-256, flushed to a fixed segment. Tournament property: any global
// top-256 key is in its block's top-256.
// key = (score_bits<<32) | ~idx -> unsigned desc == (score desc, idx asc),
// matching lax.top_k's stable tie-break.
// ---------------------------------------------------------------------------
__global__ __launch_bounds__(256)
void score_nms_kernel(const float* __restrict__ route,
                      const float* __restrict__ unc,
                      u64* __restrict__ top) {
    const int b    = blockIdx.z;
    const int tid  = threadIdx.x;
    const int w    = tid >> 6;
    const int lane = tid & 63;
    const int y0   = (blockIdx.y * 4 + w) * RPW;
    const int x0   = blockIdx.x * 256 + lane * 4;
    const int blk  = blockIdx.y * NBLKX + blockIdx.x;

    __shared__ u64 lcand[4 * WCAP];      // 16 KB, per-wave regions
    u64* myR = lcand + w * WCAP;

    const float* rB = route + (size_t)b * IMH * IMW;
    const float* uB = unc   + (size_t)b * IMH * IMW;

    int ex = -1;
    if (lane == 0)       ex = x0 - 1;
    else if (lane == 63) ex = x0 + 4;
    const bool eAct = (ex >= 0 && ex < IMW);

    const u64 laneMaskLt = (1ull << lane) - 1ull;
    int wcnt = 0;                        // wave-uniform candidate count

    float sP[4], hP1[4], hP2[4];
    #pragma unroll
    for (int j = 0; j < 4; ++j) { sP[j] = -INFINITY; hP1[j] = -INFINITY; hP2[j] = -INFINITY; }

    const int ylast = y0 + RPW;
    bool v = (y0 - 1 >= 0);
    float4 r4, u4; float er = 0.f, eu = 0.f;
    if (v) {
        r4 = *(const float4*)(rB + (size_t)(y0 - 1) * IMW + x0);
        u4 = *(const float4*)(uB + (size_t)(y0 - 1) * IMW + x0);
        if (eAct) { er = rB[(size_t)(y0 - 1) * IMW + ex]; eu = uB[(size_t)(y0 - 1) * IMW + ex]; }
    }

    for (int y = y0 - 1; y <= ylast; ++y) {
        const int yn = y + 1;
        const bool vn = (yn <= ylast) && (yn < IMH);
        float4 r4n, u4n; float ern = 0.f, eun = 0.f;
        if (vn) {
            r4n = *(const float4*)(rB + (size_t)yn * IMW + x0);
            u4n = *(const float4*)(uB + (size_t)yn * IMW + x0);
            if (eAct) { ern = rB[(size_t)yn * IMW + ex]; eun = uB[(size_t)yn * IMW + ex]; }
        }

        float sC[4], hmC[4];
        float es = -INFINITY;
        if (v && eAct) es = scoref_(er, eu);
        if (v) {
            sC[0] = scoref_(r4.x, u4.x);
            sC[1] = scoref_(r4.y, u4.y);
            sC[2] = scoref_(r4.z, u4.z);
            sC[3] = scoref_(r4.w, u4.w);
        } else {
            sC[0] = sC[1] = sC[2] = sC[3] = -INFINITY;
        }
        float lft = __shfl_up(sC[3], 1, 64);
        if (lane == 0) lft = es;
        float rgt = __shfl_down(sC[0], 1, 64);
        if (lane == 63) rgt = es;
        if (v) {
            hmC[0] = fmaxf(fmaxf(lft,   sC[0]), sC[1]);
            hmC[1] = fmaxf(fmaxf(sC[0], sC[1]), sC[2]);
            hmC[2] = fmaxf(fmaxf(sC[1], sC[2]), sC[3]);
            hmC[3] = fmaxf(fmaxf(sC[2], sC[3]), rgt);
        } else {
            hmC[0] = hmC[1] = hmC[2] = hmC[3] = -INFINITY;
        }

        if (y >= y0 + 1) {
            const int yo = y - 1;
            bool p[4]; int cntT = 0;
            #pragma unroll
            for (int j = 0; j < 4; ++j) {
                const float m9 = fmaxf(fmaxf(hP2[j], hP1[j]), hmC[j]);
                p[j] = (sP[j] >= m9);
                cntT += p[j] ? 1 : 0;
            }
            const u64 B0 = __ballot(cntT & 1);
            const u64 B1 = __ballot(cntT & 2);
            const u64 B2 = __ballot(cntT & 4);
            const int total = __popcll(B0) + 2 * __popcll(B1) + 4 * __popcll(B2);
            if (total > 0) {
                const int prefix = __popcll(B0 & laneMaskLt) + 2 * __popcll(B1 & laneMaskLt)
                                 + 4 * __popcll(B2 & laneMaskLt);
                int mb = wcnt + prefix;
                #pragma unroll
                for (int j = 0; j < 4; ++j) {
                    if (p[j]) {
                        const unsigned idx = (unsigned)(yo * IMW + (x0 + j));
                        const u64 key = ((u64)__float_as_uint(sP[j]) << 32) | (unsigned)(~idx);
                        if (mb < WCAP) myR[mb] = key;
                        ++mb;
                    }
                }
                wcnt += total;
            }
        }

        #pragma unroll
        for (int j = 0; j < 4; ++j) { hP2[j] = hP1[j]; hP1[j] = hmC[j]; sP[j] = sC[j]; }
        r4 = r4n; u4 = u4n; er = ern; eu = eun; v = vn;
    }

    __syncthreads();    // publish appends before volatile sort phase

    // ---- per-wave: zero-pad + bitonic sort 512 desc, NO barriers ----
    {
        volatile u64* R = lcand + w * WCAP;
        const int m = (wcnt < WCAP) ? wcnt : WCAP;
        for (int i = m + lane; i < WCAP; i += 64) R[i] = 0ull;
        for (int k2 = 2; k2 <= WCAP; k2 <<= 1) {
            for (int j = k2 >> 1; j > 0; j >>= 1) {
                #pragma unroll
                for (int t = 0; t < 4; ++t) {
                    const int p   = lane + (t << 6);           // 0..255
                    const int i   = ((p & ~(j - 1)) << 1) | (p & (j - 1));
                    const int ixj = i | j;
                    const u64 a = R[i];
                    const u64 c = R[ixj];
                    const bool desc = ((i & k2) == 0);
                    if (desc ? (a < c) : (a > c)) { R[i] = c; R[ixj] = a; }
                }
            }
        }
    }
    __syncthreads();

    // ---- round 1: waves 0,1 merge list pairs (0,1) and (2,3) ----
    if (w < 2) {
        volatile u64* A  = lcand + (2 * w) * WCAP;
        volatile u64* Bv = lcand + (2 * w + 1) * WCAP;
        #pragma unroll
        for (int t = 0; t < 4; ++t) {
            const int i = lane + (t << 6);                     // 0..255
            const u64 a = A[i];
            const u64 c = Bv[KMAX - 1 - i];
            A[i] = (a > c) ? a : c;
        }
        for (int j = KMAX >> 1; j > 0; j >>= 1) {
            #pragma unroll
            for (int t = 0; t < 2; ++t) {
                const int p   = lane + (t << 6);               // 0..127
                const int i   = ((p & ~(j - 1)) << 1) | (p & (j - 1));
                const int ixj = i | j;
                const u64 a = A[i];
                const u64 c = A[ixj];
                if (a < c) { A[i] = c; A[ixj] = a; }
            }
        }
    }
    __syncthreads();

    // ---- round 2: wave 0 merges (0, 2) ----
    if (w == 0) {
        volatile u64* A  = lcand;
        volatile u64* Bv = lcand + 2 * WCAP;
        #pragma unroll
        for (int t = 0; t < 4; ++t) {
            const int i = lane + (t << 6);
            const u64 a = A[i];
            const u64 c = Bv[KMAX - 1 - i];
            A[i] = (a > c) ? a : c;
        }
        for (int j = KMAX >> 1; j > 0; j >>= 1) {
            #pragma unroll
            for (int t = 0; t < 2; ++t) {
                const int p   = lane + (t << 6);
                const int i   = ((p & ~(j - 1)) << 1) | (p & (j - 1));
                const int ixj = i | j;
                const u64 a = A[i];
                const u64 c = A[ixj];
                if (a < c) { A[i] = c; A[ixj] = a; }
            }
        }
    }
    __syncthreads();

    // flush the block's sorted top-256 (fixed segment, no counts)
    top[((size_t)b * NBLK + blk) * KMAX + tid] = lcand[tid];
}

// ---------------------------------------------------------------------------
// K2 (tail): 1 block/image x 512 threads. 32 sorted-desc 256-lists ->
// 5 rounds of pairwise top-256 merge (D[i] = max(A[i], B[255-i]) + 8-phase
// bitonic clean). Final list = exact sorted global top-256 -> ROI epilogue.
// ---------------------------------------------------------------------------
__global__ __launch_bounds__(TPB2)
void tail_kernel(const u64* __restrict__ top,
                 const float* __restrict__ scale,
                 const float* __restrict__ unc,
                 const int* __restrict__ imh,
                 const int* __restrict__ imw,
                 float* __restrict__ rois,
                 float* __restrict__ scoresOut,
                 float* __restrict__ validOut) {
    const int b   = blockIdx.x;
    const int tid = threadIdx.x;

    __shared__ u64 bufA[NBLK * KMAX];        // 64 KB
    __shared__ u64 bufB[(NBLK / 2) * KMAX];  // 32 KB

    const u64* tb = top + (size_t)b * NBLK * KMAX;
    for (int i = tid; i < NBLK * KMAX; i += TPB2) bufA[i] = tb[i];
    __syncthreads();

    u64* src = bufA;
    u64* dst = bufB;
    int nl = NBLK;
    while (nl > 1) {
        const int half = nl >> 1;
        const int E = half * KMAX;
        for (int p = tid; p < E; p += TPB2) {
            const int h = p >> 8;
            const int i = p & (KMAX - 1);
            const u64 a = src[(2 * h) * KMAX + i];
            const u64 c = src[(2 * h + 1) * KMAX + (KMAX - 1 - i)];
            dst[p] = (a > c) ? a : c;
        }
        __syncthreads();
        for (int j = KMAX >> 1; j > 0; j >>= 1) {
            for (int p = tid; p < (E >> 1); p += TPB2) {
                const int i   = ((p & ~(j - 1)) << 1) | (p & (j - 1));
                const int ixj = i | j;
                const u64 a = dst[i];
                const u64 c = dst[ixj];
                if (a < c) { dst[i] = c; dst[ixj] = a; }
            }
            __syncthreads();
        }
        u64* t = src; src = dst; dst = t;
        nl = half;
    }

    if (tid < KMAX) {
        const u64 k = src[tid];
        const float value = __uint_as_float((unsigned)(k >> 32));
        const bool valid  = (k != 0ull) && (value > 0.0f);

        float r0 = 0.f, r1 = 0.f, r2 = 0.f, r3 = 0.f, r4 = 0.f, sv = 0.f, vv = 0.f;
        if (valid) {
            const unsigned idx = ~(unsigned)(k & 0xFFFFFFFFull);
            const int y = (int)(idx / IMW);
            const int x = (int)(idx % IMW);
            const float cx = ((float)x + 0.5f) * 4.0f;
            const float cy = ((float)y + 0.5f) * 4.0f;
            const float sg = scale[(size_t)b * IMH * IMW + idx];
            const float uu = unc[(size_t)b * IMH * IMW + idx];
            const float su = sigmoidf_(uu);
            float side = 32.0f + sigmoidf_(sg) * (512.0f - 32.0f);
            side = side * (1.0f + 0.25f * su);
            const float half2 = side * 0.5f;
            const float fw = (float)imw[0];
            const float fh = (float)imh[0];
            r0 = (float)b;
            r1 = fminf(fmaxf(cx - half2, 0.0f), fw - 1.0f);
            r2 = fminf(fmaxf(cy - half2, 0.0f), fh - 1.0f);
            r3 = fminf(fmaxf(cx + half2, 1.0f), fw);
            r4 = fminf(fmaxf(cy + half2, 1.0f), fh);
            sv = value;
            vv = 1.0f;
        }
        float* roiP = rois + ((size_t)b * KMAX + tid) * 5;
        roiP[0] = r0; roiP[1] = r1; roiP[2] = r2; roiP[3] = r3; roiP[4] = r4;
        scoresOut[b * KMAX + tid] = sv;
        validOut[b * KMAX + tid]  = vv;
    }
}

extern "C" void kernel_launch(void* const* d_in, const int* in_sizes, int n_in,
                              void* d_out, int out_size, void* d_ws, size_t ws_size,
                              hipStream_t stream) {
    const float* route = (const float*)d_in[0];
    const float* scale = (const float*)d_in[1];
    const float* unc   = (const float*)d_in[2];
    const int*   imh   = (const int*)d_in[3];
    const int*   imw   = (const int*)d_in[4];

    // ws layout: [top B*NBLK*256 u64] = 2 MB
    u64* top = (u64*)d_ws;

    float* rois      = (float*)d_out;                       // [B, 256, 5]
    float* scoresOut = rois + (size_t)BATCH * KMAX * 5;     // [B, 256]
    float* validOut  = scoresOut + (size_t)BATCH * KMAX;    // [B, 256]

    dim3 grid1(NBLKX, NBLKY, BATCH);
    score_nms_kernel<<<grid1, 256, 0, stream>>>(route, unc, top);

    tail_kernel<<<BATCH, TPB2, 0, stream>>>(top, scale, unc,
                                            imh, imw, rois, scoresOut, validOut);
}

// Round 15
// 82.273 us; speedup vs baseline: 1.3437x; 1.3437x over previous
//
#include <hip/hip_runtime.h>
#include <cstdint>
#include <cstddef>

#define BATCH 32
#define IMH 512
#define IMW 512
#define KMAX 256

// K1: register rolling-window NMS. Wave = 256 cols (4/lane), RPW output rows.
#define RPW 8
#define NBLKX 2
#define NBLKY 16
#define NBLK (NBLKX * NBLKY)   // 32 blocks/image
#define WCAP 512               // per-wave candidate cap = worst-case strict maxima in 256x8

#define TPB2 512               // tail threads (8 waves)

typedef unsigned long long u64;

__device__ __forceinline__ float sigmoidf_(float x) {
    return 1.0f / (1.0f + expf(-x));
}
__device__ __forceinline__ float scoref_(float r, float u) {
    const float sg = sigmoidf_(r);
    return sg * sg * (1.0f - 0.35f * sigmoidf_(u));
}

// ---------------------------------------------------------------------------
// Wave-level bitonic sort DESCENDING of NR*64 elements held in registers:
// element e = r*64 + lane. Strides j<64 -> shfl_xor; j>=64 -> register swap.
// Zero LDS traffic, zero barriers, deterministic.
// ---------------------------------------------------------------------------
template <int NR>
__device__ __forceinline__ void wave_sort_desc(u64* val, const int lane) {
    const int N = NR * 64;
    for (int k = 2; k <= N; k <<= 1) {
        for (int j = k >> 1; j > 0; j >>= 1) {
            if (j >= 64) {
                const int jr = j >> 6;
                #pragma unroll
                for (int r = 0; r < NR; ++r) {
                    const int rr = r ^ jr;
                    if (rr > r) {
                        const bool mx = ((r & (k >> 6)) == 0);   // (e & k)==0, lane bits < 64
                        const u64 a = val[r], b = val[rr];
                        const u64 hi = (a > b) ? a : b;
                        const u64 lo = (a > b) ? b : a;
                        val[r]  = mx ? hi : lo;
                        val[rr] = mx ? lo : hi;
                    }
                }
            } else {
                #pragma unroll
                for (int r = 0; r < NR; ++r) {
                    const u64 other = __shfl_xor(val[r], j, 64);
                    const bool lower  = ((lane & j) == 0);
                    const bool dirMax = ((((r << 6) | lane) & k) == 0);
                    const u64 mn  = (val[r] < other) ? val[r] : other;
                    const u64 mxv = (val[r] < other) ? other  : val[r];
                    val[r] = (lower == dirMax) ? mxv : mn;
                }
            }
        }
    }
}

// ---------------------------------------------------------------------------
// K1: fused score + 3x3 NMS (register rolling window). Each WAVE appends to a
// private 512-slot LDS region (register counter + ballot prefix, no atomics),
// REGISTER-bitonic-sorts its candidates (N=256 fast path / N=512), writes its
// sorted top-256 back, then 2 pairwise top-256 merge rounds (3 barriers)
// produce the block's sorted top-256. Tournament property: any global top-256
// key is in its block's top-256.
// key = (score_bits<<32) | ~idx -> unsigned desc == (score desc, idx asc),
// matching lax.top_k's stable tie-break.
// ---------------------------------------------------------------------------
__global__ __launch_bounds__(256)
void score_nms_kernel(const float* __restrict__ route,
                      const float* __restrict__ unc,
                      u64* __restrict__ top) {
    const int b    = blockIdx.z;
    const int tid  = threadIdx.x;
    const int w    = tid >> 6;
    const int lane = tid & 63;
    const int y0   = (blockIdx.y * 4 + w) * RPW;
    const int x0   = blockIdx.x * 256 + lane * 4;
    const int blk  = blockIdx.y * NBLKX + blockIdx.x;

    __shared__ u64 lcand[4 * WCAP];      // 16 KB, per-wave regions
    u64* myR = lcand + w * WCAP;

    const float* rB = route + (size_t)b * IMH * IMW;
    const float* uB = unc   + (size_t)b * IMH * IMW;

    int ex = -1;
    if (lane == 0)       ex = x0 - 1;
    else if (lane == 63) ex = x0 + 4;
    const bool eAct = (ex >= 0 && ex < IMW);

    const u64 laneMaskLt = (1ull << lane) - 1ull;
    int wcnt = 0;                        // wave-uniform candidate count

    float sP[4], hP1[4], hP2[4];
    #pragma unroll
    for (int j = 0; j < 4; ++j) { sP[j] = -INFINITY; hP1[j] = -INFINITY; hP2[j] = -INFINITY; }

    const int ylast = y0 + RPW;
    bool v = (y0 - 1 >= 0);
    float4 r4, u4; float er = 0.f, eu = 0.f;
    if (v) {
        r4 = *(const float4*)(rB + (size_t)(y0 - 1) * IMW + x0);
        u4 = *(const float4*)(uB + (size_t)(y0 - 1) * IMW + x0);
        if (eAct) { er = rB[(size_t)(y0 - 1) * IMW + ex]; eu = uB[(size_t)(y0 - 1) * IMW + ex]; }
    }

    for (int y = y0 - 1; y <= ylast; ++y) {
        const int yn = y + 1;
        const bool vn = (yn <= ylast) && (yn < IMH);
        float4 r4n, u4n; float ern = 0.f, eun = 0.f;
        if (vn) {
            r4n = *(const float4*)(rB + (size_t)yn * IMW + x0);
            u4n = *(const float4*)(uB + (size_t)yn * IMW + x0);
            if (eAct) { ern = rB[(size_t)yn * IMW + ex]; eun = uB[(size_t)yn * IMW + ex]; }
        }

        float sC[4], hmC[4];
        float es = -INFINITY;
        if (v && eAct) es = scoref_(er, eu);
        if (v) {
            sC[0] = scoref_(r4.x, u4.x);
            sC[1] = scoref_(r4.y, u4.y);
            sC[2] = scoref_(r4.z, u4.z);
            sC[3] = scoref_(r4.w, u4.w);
        } else {
            sC[0] = sC[1] = sC[2] = sC[3] = -INFINITY;
        }
        float lft = __shfl_up(sC[3], 1, 64);
        if (lane == 0) lft = es;
        float rgt = __shfl_down(sC[0], 1, 64);
        if (lane == 63) rgt = es;
        if (v) {
            hmC[0] = fmaxf(fmaxf(lft,   sC[0]), sC[1]);
            hmC[1] = fmaxf(fmaxf(sC[0], sC[1]), sC[2]);
            hmC[2] = fmaxf(fmaxf(sC[1], sC[2]), sC[3]);
            hmC[3] = fmaxf(fmaxf(sC[2], sC[3]), rgt);
        } else {
            hmC[0] = hmC[1] = hmC[2] = hmC[3] = -INFINITY;
        }

        if (y >= y0 + 1) {
            const int yo = y - 1;
            bool p[4]; int cntT = 0;
            #pragma unroll
            for (int j = 0; j < 4; ++j) {
                const float m9 = fmaxf(fmaxf(hP2[j], hP1[j]), hmC[j]);
                p[j] = (sP[j] >= m9);
                cntT += p[j] ? 1 : 0;
            }
            const u64 B0 = __ballot(cntT & 1);
            const u64 B1 = __ballot(cntT & 2);
            const u64 B2 = __ballot(cntT & 4);
            const int total = __popcll(B0) + 2 * __popcll(B1) + 4 * __popcll(B2);
            if (total > 0) {
                const int prefix = __popcll(B0 & laneMaskLt) + 2 * __popcll(B1 & laneMaskLt)
                                 + 4 * __popcll(B2 & laneMaskLt);
                int mb = wcnt + prefix;
                #pragma unroll
                for (int j = 0; j < 4; ++j) {
                    if (p[j]) {
                        const unsigned idx = (unsigned)(yo * IMW + (x0 + j));
                        const u64 key = ((u64)__float_as_uint(sP[j]) << 32) | (unsigned)(~idx);
                        if (mb < WCAP) myR[mb] = key;
                        ++mb;
                    }
                }
                wcnt += total;
            }
        }

        #pragma unroll
        for (int j = 0; j < 4; ++j) { hP2[j] = hP1[j]; hP1[j] = hmC[j]; sP[j] = sC[j]; }
        r4 = r4n; u4 = u4n; er = ern; eu = eun; v = vn;
    }

    __syncthreads();    // appends visible before register loads

    // ---- per-wave: register bitonic sort (N=256 fast path / N=512) ----
    const int m = (wcnt < WCAP) ? wcnt : WCAP;
    if (m <= 256) {
        u64 val[4];
        #pragma unroll
        for (int r = 0; r < 4; ++r) {
            const int e = r * 64 + lane;
            val[r] = (e < m) ? myR[e] : 0ull;
        }
        wave_sort_desc<4>(val, lane);
        #pragma unroll
        for (int r = 0; r < 4; ++r) myR[r * 64 + lane] = val[r];
    } else {
        u64 val[8];
        #pragma unroll
        for (int r = 0; r < 8; ++r) {
            const int e = r * 64 + lane;
            val[r] = (e < m) ? myR[e] : 0ull;
        }
        wave_sort_desc<8>(val, lane);
        #pragma unroll
        for (int r = 0; r < 4; ++r) myR[r * 64 + lane] = val[r];   // top-256 only
    }
    __syncthreads();

    // ---- round 1: waves 0,1 merge list pairs (0,1) and (2,3) ----
    if (w < 2) {
        volatile u64* A  = lcand + (2 * w) * WCAP;
        volatile u64* Bv = lcand + (2 * w + 1) * WCAP;
        #pragma unroll
        for (int t = 0; t < 4; ++t) {
            const int i = lane + (t << 6);                     // 0..255
            const u64 a = A[i];
            const u64 c = Bv[KMAX - 1 - i];
            A[i] = (a > c) ? a : c;
        }
        for (int j = KMAX >> 1; j > 0; j >>= 1) {
            #pragma unroll
            for (int t = 0; t < 2; ++t) {
                const int p   = lane + (t << 6);               // 0..127
                const int i   = ((p & ~(j - 1)) << 1) | (p & (j - 1));
                const int ixj = i | j;
                const u64 a = A[i];
                const u64 c = A[ixj];
                if (a < c) { A[i] = c; A[ixj] = a; }
            }
        }
    }
    __syncthreads();

    // ---- round 2: wave 0 merges (0, 2) ----
    if (w == 0) {
        volatile u64* A  = lcand;
        volatile u64* Bv = lcand + 2 * WCAP;
        #pragma unroll
        for (int t = 0; t < 4; ++t) {
            const int i = lane + (t << 6);
            const u64 a = A[i];
            const u64 c = Bv[KMAX - 1 - i];
            A[i] = (a > c) ? a : c;
        }
        for (int j = KMAX >> 1; j > 0; j >>= 1) {
            #pragma unroll
            for (int t = 0; t < 2; ++t) {
                const int p   = lane + (t << 6);
                const int i   = ((p & ~(j - 1)) << 1) | (p & (j - 1));
                const int ixj = i | j;
                const u64 a = A[i];
                const u64 c = A[ixj];
                if (a < c) { A[i] = c; A[ixj] = a; }
            }
        }
    }
    __syncthreads();

    // flush the block's sorted top-256 (fixed segment, no counts)
    top[((size_t)b * NBLK + blk) * KMAX + tid] = lcand[tid];
}

// ---------------------------------------------------------------------------
// K2 (tail): 1 block/image x 512 threads. 32 sorted-desc 256-lists ->
// 5 rounds of pairwise top-256 merge (D[i] = max(A[i], B[255-i]) + 8-phase
// bitonic clean). Final list = exact sorted global top-256 -> ROI epilogue.
// ---------------------------------------------------------------------------
__global__ __launch_bounds__(TPB2)
void tail_kernel(const u64* __restrict__ top,
                 const float* __restrict__ scale,
                 const float* __restrict__ unc,
                 const int* __restrict__ imh,
                 const int* __restrict__ imw,
                 float* __restrict__ rois,
                 float* __restrict__ scoresOut,
                 float* __restrict__ validOut) {
    const int b   = blockIdx.x;
    const int tid = threadIdx.x;

    __shared__ u64 bufA[NBLK * KMAX];        // 64 KB
    __shared__ u64 bufB[(NBLK / 2) * KMAX];  // 32 KB

    const u64* tb = top + (size_t)b * NBLK * KMAX;
    for (int i = tid; i < NBLK * KMAX; i += TPB2) bufA[i] = tb[i];
    __syncthreads();

    u64* src = bufA;
    u64* dst = bufB;
    int nl = NBLK;
    while (nl > 1) {
        const int half = nl >> 1;
        const int E = half * KMAX;
        for (int p = tid; p < E; p += TPB2) {
            const int h = p >> 8;
            const int i = p & (KMAX - 1);
            const u64 a = src[(2 * h) * KMAX + i];
            const u64 c = src[(2 * h + 1) * KMAX + (KMAX - 1 - i)];
            dst[p] = (a > c) ? a : c;
        }
        __syncthreads();
        for (int j = KMAX >> 1; j > 0; j >>= 1) {
            for (int p = tid; p < (E >> 1); p += TPB2) {
                const int i   = ((p & ~(j - 1)) << 1) | (p & (j - 1));
                const int ixj = i | j;
                const u64 a = dst[i];
                const u64 c = dst[ixj];
                if (a < c) { dst[i] = c; dst[ixj] = a; }
            }
            __syncthreads();
        }
        u64* t = src; src = dst; dst = t;
        nl = half;
    }

    if (tid < KMAX) {
        const u64 k = src[tid];
        const float value = __uint_as_float((unsigned)(k >> 32));
        const bool valid  = (k != 0ull) && (value > 0.0f);

        float r0 = 0.f, r1 = 0.f, r2 = 0.f, r3 = 0.f, r4 = 0.f, sv = 0.f, vv = 0.f;
        if (valid) {
            const unsigned idx = ~(unsigned)(k & 0xFFFFFFFFull);
            const int y = (int)(idx / IMW);
            const int x = (int)(idx % IMW);
            const float cx = ((float)x + 0.5f) * 4.0f;
            const float cy = ((float)y + 0.5f) * 4.0f;
            const float sg = scale[(size_t)b * IMH * IMW + idx];
            const float uu = unc[(size_t)b * IMH * IMW + idx];
            const float su = sigmoidf_(uu);
            float side = 32.0f + sigmoidf_(sg) * (512.0f - 32.0f);
            side = side * (1.0f + 0.25f * su);
            const float half2 = side * 0.5f;
            const float fw = (float)imw[0];
            const float fh = (float)imh[0];
            r0 = (float)b;
            r1 = fminf(fmaxf(cx - half2, 0.0f), fw - 1.0f);
            r2 = fminf(fmaxf(cy - half2, 0.0f), fh - 1.0f);
            r3 = fminf(fmaxf(cx + half2, 1.0f), fw);
            r4 = fminf(fmaxf(cy + half2, 1.0f), fh);
            sv = value;
            vv = 1.0f;
        }
        float* roiP = rois + ((size_t)b * KMAX + tid) * 5;
        roiP[0] = r0; roiP[1] = r1; roiP[2] = r2; roiP[3] = r3; roiP[4] = r4;
        scoresOut[b * KMAX + tid] = sv;
        validOut[b * KMAX + tid]  = vv;
    }
}

extern "C" void kernel_launch(void* const* d_in, const int* in_sizes, int n_in,
                              void* d_out, int out_size, void* d_ws, size_t ws_size,
                              hipStream_t stream) {
    const float* route = (const float*)d_in[0];
    const float* scale = (const float*)d_in[1];
    const float* unc   = (const float*)d_in[2];
    const int*   imh   = (const int*)d_in[3];
    const int*   imw   = (const int*)d_in[4];

    // ws layout: [top B*NBLK*256 u64] = 2 MB
    u64* top = (u64*)d_ws;

    float* rois      = (float*)d_out;                       // [B, 256, 5]
    float* scoresOut = rois + (size_t)BATCH * KMAX * 5;     // [B, 256]
    float* validOut  = scoresOut + (size_t)BATCH * KMAX;    // [B, 256]

    dim3 grid1(NBLKX, NBLKY, BATCH);
    score_nms_kernel<<<grid1, 256, 0, stream>>>(route, unc, top);

    tail_kernel<<<BATCH, TPB2, 0, stream>>>(top, scale, unc,
                                            imh, imw, rois, scoresOut, validOut);
}

// Round 16
// 73.819 us; speedup vs baseline: 1.4976x; 1.1145x over previous
//
#include <hip/hip_runtime.h>
#include <cstdint>
#include <cstddef>

#define BATCH 32
#define IMH 512
#define IMW 512
#define KMAX 256

// K1: register rolling-window NMS. Wave = 256 cols (4/lane), RPW output rows.
#define RPW 8
#define NBLKX 2
#define NBLKY 16
#define NBLK (NBLKX * NBLKY)   // 32 blocks/image
#define WCAP 512               // per-wave candidate cap = worst-case strict maxima in 256x8

#define TPB2 512               // tail threads (8 waves)

typedef unsigned long long u64;

__device__ __forceinline__ float sigmoidf_(float x) {
    return 1.0f / (1.0f + expf(-x));
}
__device__ __forceinline__ float scoref_(float r, float u) {
    const float sg = sigmoidf_(r);
    return sg * sg * (1.0f - 0.35f * sigmoidf_(u));
}

// ---------------------------------------------------------------------------
// Wave-level bitonic sort DESCENDING of NR*64 elements held in registers:
// element e = r*64 + lane. Strides j<64 -> shfl_xor; j>=64 -> register swap.
// FULLY UNROLLED (k, j compile-time) so all val[] indices are static and the
// array stays in VGPRs (runtime-indexed arrays demote to scratch — rule #20).
// ---------------------------------------------------------------------------
template <int NR>
__device__ __forceinline__ void wave_sort_desc(u64* val, const int lane) {
    constexpr int N = NR * 64;
    #pragma unroll
    for (int k = 2; k <= N; k <<= 1) {
        #pragma unroll
        for (int j = k >> 1; j > 0; j >>= 1) {
            if (j >= 64) {
                const int jr = j >> 6;           // compile-time after unroll
                #pragma unroll
                for (int r = 0; r < NR; ++r) {
                    const int rr = r ^ jr;
                    if (rr > r) {
                        const bool mx = ((r & (k >> 6)) == 0);
                        const u64 a = val[r], b = val[rr];
                        const u64 hi = (a > b) ? a : b;
                        const u64 lo = (a > b) ? b : a;
                        val[r]  = mx ? hi : lo;
                        val[rr] = mx ? lo : hi;
                    }
                }
            } else {
                #pragma unroll
                for (int r = 0; r < NR; ++r) {
                    const u64 other = __shfl_xor(val[r], j, 64);
                    const bool lower  = ((lane & j) == 0);
                    const bool dirMax = ((((r << 6) | lane) & k) == 0);
                    const u64 mn  = (val[r] < other) ? val[r] : other;
                    const u64 mxv = (val[r] < other) ? other  : val[r];
                    val[r] = (lower == dirMax) ? mxv : mn;
                }
            }
        }
    }
}

// ---------------------------------------------------------------------------
// K1: fused score + 3x3 NMS (register rolling window). Each WAVE appends to a
// private 512-slot LDS region (register counter + ballot prefix, no atomics),
// register-bitonic-sorts its candidates (N=256 fast path / N=512), writes its
// sorted top-256 back, then 2 pairwise top-256 merge rounds (3 barriers)
// produce the block's sorted top-256. Tournament property: any global top-256
// key is in its block's top-256.
// key = (score_bits<<32) | ~idx -> unsigned desc == (score desc, idx asc),
// matching lax.top_k's stable tie-break.
// ---------------------------------------------------------------------------
__global__ __launch_bounds__(256)
void score_nms_kernel(const float* __restrict__ route,
                      const float* __restrict__ unc,
                      u64* __restrict__ top) {
    const int b    = blockIdx.z;
    const int tid  = threadIdx.x;
    const int w    = tid >> 6;
    const int lane = tid & 63;
    const int y0   = (blockIdx.y * 4 + w) * RPW;
    const int x0   = blockIdx.x * 256 + lane * 4;
    const int blk  = blockIdx.y * NBLKX + blockIdx.x;

    __shared__ u64 lcand[4 * WCAP];      // 16 KB, per-wave regions
    u64* myR = lcand + w * WCAP;

    const float* rB = route + (size_t)b * IMH * IMW;
    const float* uB = unc   + (size_t)b * IMH * IMW;

    int ex = -1;
    if (lane == 0)       ex = x0 - 1;
    else if (lane == 63) ex = x0 + 4;
    const bool eAct = (ex >= 0 && ex < IMW);

    const u64 laneMaskLt = (1ull << lane) - 1ull;
    int wcnt = 0;                        // wave-uniform candidate count

    float sP[4], hP1[4], hP2[4];
    #pragma unroll
    for (int j = 0; j < 4; ++j) { sP[j] = -INFINITY; hP1[j] = -INFINITY; hP2[j] = -INFINITY; }

    const int ylast = y0 + RPW;
    bool v = (y0 - 1 >= 0);
    float4 r4, u4; float er = 0.f, eu = 0.f;
    if (v) {
        r4 = *(const float4*)(rB + (size_t)(y0 - 1) * IMW + x0);
        u4 = *(const float4*)(uB + (size_t)(y0 - 1) * IMW + x0);
        if (eAct) { er = rB[(size_t)(y0 - 1) * IMW + ex]; eu = uB[(size_t)(y0 - 1) * IMW + ex]; }
    }

    for (int y = y0 - 1; y <= ylast; ++y) {
        const int yn = y + 1;
        const bool vn = (yn <= ylast) && (yn < IMH);
        float4 r4n, u4n; float ern = 0.f, eun = 0.f;
        if (vn) {
            r4n = *(const float4*)(rB + (size_t)yn * IMW + x0);
            u4n = *(const float4*)(uB + (size_t)yn * IMW + x0);
            if (eAct) { ern = rB[(size_t)yn * IMW + ex]; eun = uB[(size_t)yn * IMW + ex]; }
        }

        float sC[4], hmC[4];
        float es = -INFINITY;
        if (v && eAct) es = scoref_(er, eu);
        if (v) {
            sC[0] = scoref_(r4.x, u4.x);
            sC[1] = scoref_(r4.y, u4.y);
            sC[2] = scoref_(r4.z, u4.z);
            sC[3] = scoref_(r4.w, u4.w);
        } else {
            sC[0] = sC[1] = sC[2] = sC[3] = -INFINITY;
        }
        float lft = __shfl_up(sC[3], 1, 64);
        if (lane == 0) lft = es;
        float rgt = __shfl_down(sC[0], 1, 64);
        if (lane == 63) rgt = es;
        if (v) {
            hmC[0] = fmaxf(fmaxf(lft,   sC[0]), sC[1]);
            hmC[1] = fmaxf(fmaxf(sC[0], sC[1]), sC[2]);
            hmC[2] = fmaxf(fmaxf(sC[1], sC[2]), sC[3]);
            hmC[3] = fmaxf(fmaxf(sC[2], sC[3]), rgt);
        } else {
            hmC[0] = hmC[1] = hmC[2] = hmC[3] = -INFINITY;
        }

        if (y >= y0 + 1) {
            const int yo = y - 1;
            bool p[4]; int cntT = 0;
            #pragma unroll
            for (int j = 0; j < 4; ++j) {
                const float m9 = fmaxf(fmaxf(hP2[j], hP1[j]), hmC[j]);
                p[j] = (sP[j] >= m9);
                cntT += p[j] ? 1 : 0;
            }
            const u64 B0 = __ballot(cntT & 1);
            const u64 B1 = __ballot(cntT & 2);
            const u64 B2 = __ballot(cntT & 4);
            const int total = __popcll(B0) + 2 * __popcll(B1) + 4 * __popcll(B2);
            if (total > 0) {
                const int prefix = __popcll(B0 & laneMaskLt) + 2 * __popcll(B1 & laneMaskLt)
                                 + 4 * __popcll(B2 & laneMaskLt);
                int mb = wcnt + prefix;
                #pragma unroll
                for (int j = 0; j < 4; ++j) {
                    if (p[j]) {
                        const unsigned idx = (unsigned)(yo * IMW + (x0 + j));
                        const u64 key = ((u64)__float_as_uint(sP[j]) << 32) | (unsigned)(~idx);
                        if (mb < WCAP) myR[mb] = key;
                        ++mb;
                    }
                }
                wcnt += total;
            }
        }

        #pragma unroll
        for (int j = 0; j < 4; ++j) { hP2[j] = hP1[j]; hP1[j] = hmC[j]; sP[j] = sC[j]; }
        r4 = r4n; u4 = u4n; er = ern; eu = eun; v = vn;
    }

    __syncthreads();    // appends visible before register loads

    // ---- per-wave: register bitonic sort (N=256 fast path / N=512) ----
    const int m = (wcnt < WCAP) ? wcnt : WCAP;
    if (m <= 256) {
        u64 val[4];
        #pragma unroll
        for (int r = 0; r < 4; ++r) {
            const int e = r * 64 + lane;
            val[r] = (e < m) ? myR[e] : 0ull;
        }
        wave_sort_desc<4>(val, lane);
        #pragma unroll
        for (int r = 0; r < 4; ++r) myR[r * 64 + lane] = val[r];
    } else {
        u64 val[8];
        #pragma unroll
        for (int r = 0; r < 8; ++r) {
            const int e = r * 64 + lane;
            val[r] = (e < m) ? myR[e] : 0ull;
        }
        wave_sort_desc<8>(val, lane);
        #pragma unroll
        for (int r = 0; r < 4; ++r) myR[r * 64 + lane] = val[r];   // top-256 only
    }
    __syncthreads();

    // ---- round 1: waves 0,1 merge list pairs (0,1) and (2,3) ----
    if (w < 2) {
        volatile u64* A  = lcand + (2 * w) * WCAP;
        volatile u64* Bv = lcand + (2 * w + 1) * WCAP;
        #pragma unroll
        for (int t = 0; t < 4; ++t) {
            const int i = lane + (t << 6);                     // 0..255
            const u64 a = A[i];
            const u64 c = Bv[KMAX - 1 - i];
            A[i] = (a > c) ? a : c;
        }
        for (int j = KMAX >> 1; j > 0; j >>= 1) {
            #pragma unroll
            for (int t = 0; t < 2; ++t) {
                const int p   = lane + (t << 6);               // 0..127
                const int i   = ((p & ~(j - 1)) << 1) | (p & (j - 1));
                const int ixj = i | j;
                const u64 a = A[i];
                const u64 c = A[ixj];
                if (a < c) { A[i] = c; A[ixj] = a; }
            }
        }
    }
    __syncthreads();

    // ---- round 2: wave 0 merges (0, 2) ----
    if (w == 0) {
        volatile u64* A  = lcand;
        volatile u64* Bv = lcand + 2 * WCAP;
        #pragma unroll
        for (int t = 0; t < 4; ++t) {
            const int i = lane + (t << 6);
            const u64 a = A[i];
            const u64 c = Bv[KMAX - 1 - i];
            A[i] = (a > c) ? a : c;
        }
        for (int j = KMAX >> 1; j > 0; j >>= 1) {
            #pragma unroll
            for (int t = 0; t < 2; ++t) {
                const int p   = lane + (t << 6);
                const int i   = ((p & ~(j - 1)) << 1) | (p & (j - 1));
                const int ixj = i | j;
                const u64 a = A[i];
                const u64 c = A[ixj];
                if (a < c) { A[i] = c; A[ixj] = a; }
            }
        }
    }
    __syncthreads();

    // flush the block's sorted top-256 (fixed segment, no counts)
    top[((size_t)b * NBLK + blk) * KMAX + tid] = lcand[tid];
}

// ---------------------------------------------------------------------------
// K2 (tail): 1 block/image x 512 threads. 32 sorted-desc 256-lists ->
// 5 rounds of pairwise top-256 merge (D[i] = max(A[i], B[255-i]) + 8-phase
// bitonic clean). Final list = exact sorted global top-256 -> ROI epilogue.
// ---------------------------------------------------------------------------
__global__ __launch_bounds__(TPB2)
void tail_kernel(const u64* __restrict__ top,
                 const float* __restrict__ scale,
                 const float* __restrict__ unc,
                 const int* __restrict__ imh,
                 const int* __restrict__ imw,
                 float* __restrict__ rois,
                 float* __restrict__ scoresOut,
                 float* __restrict__ validOut) {
    const int b   = blockIdx.x;
    const int tid = threadIdx.x;

    __shared__ u64 bufA[NBLK * KMAX];        // 64 KB
    __shared__ u64 bufB[(NBLK / 2) * KMAX];  // 32 KB

    const u64* tb = top + (size_t)b * NBLK * KMAX;
    for (int i = tid; i < NBLK * KMAX; i += TPB2) bufA[i] = tb[i];
    __syncthreads();

    u64* src = bufA;
    u64* dst = bufB;
    int nl = NBLK;
    while (nl > 1) {
        const int half = nl >> 1;
        const int E = half * KMAX;
        for (int p = tid; p < E; p += TPB2) {
            const int h = p >> 8;
            const int i = p & (KMAX - 1);
            const u64 a = src[(2 * h) * KMAX + i];
            const u64 c = src[(2 * h + 1) * KMAX + (KMAX - 1 - i)];
            dst[p] = (a > c) ? a : c;
        }
        __syncthreads();
        for (int j = KMAX >> 1; j > 0; j >>= 1) {
            for (int p = tid; p < (E >> 1); p += TPB2) {
                const int i   = ((p & ~(j - 1)) << 1) | (p & (j - 1));
                const int ixj = i | j;
                const u64 a = dst[i];
                const u64 c = dst[ixj];
                if (a < c) { dst[i] = c; dst[ixj] = a; }
            }
            __syncthreads();
        }
        u64* t = src; src = dst; dst = t;
        nl = half;
    }

    if (tid < KMAX) {
        const u64 k = src[tid];
        const float value = __uint_as_float((unsigned)(k >> 32));
        const bool valid  = (k != 0ull) && (value > 0.0f);

        float r0 = 0.f, r1 = 0.f, r2 = 0.f, r3 = 0.f, r4 = 0.f, sv = 0.f, vv = 0.f;
        if (valid) {
            const unsigned idx = ~(unsigned)(k & 0xFFFFFFFFull);
            const int y = (int)(idx / IMW);
            const int x = (int)(idx % IMW);
            const float cx = ((float)x + 0.5f) * 4.0f;
            const float cy = ((float)y + 0.5f) * 4.0f;
            const float sg = scale[(size_t)b * IMH * IMW + idx];
            const float uu = unc[(size_t)b * IMH * IMW + idx];
            const float su = sigmoidf_(uu);
            float side = 32.0f + sigmoidf_(sg) * (512.0f - 32.0f);
            side = side * (1.0f + 0.25f * su);
            const float half2 = side * 0.5f;
            const float fw = (float)imw[0];
            const float fh = (float)imh[0];
            r0 = (float)b;
            r1 = fminf(fmaxf(cx - half2, 0.0f), fw - 1.0f);
            r2 = fminf(fmaxf(cy - half2, 0.0f), fh - 1.0f);
            r3 = fminf(fmaxf(cx + half2, 1.0f), fw);
            r4 = fminf(fmaxf(cy + half2, 1.0f), fh);
            sv = value;
            vv = 1.0f;
        }
        float* roiP = rois + ((size_t)b * KMAX + tid) * 5;
        roiP[0] = r0; roiP[1] = r1; roiP[2] = r2; roiP[3] = r3; roiP[4] = r4;
        scoresOut[b * KMAX + tid] = sv;
        validOut[b * KMAX + tid]  = vv;
    }
}

extern "C" void kernel_launch(void* const* d_in, const int* in_sizes, int n_in,
                              void* d_out, int out_size, void* d_ws, size_t ws_size,
                              hipStream_t stream) {
    const float* route = (const float*)d_in[0];
    const float* scale = (const float*)d_in[1];
    const float* unc   = (const float*)d_in[2];
    const int*   imh   = (const int*)d_in[3];
    const int*   imw   = (const int*)d_in[4];

    // ws layout: [top B*NBLK*256 u64] = 2 MB
    u64* top = (u64*)d_ws;

    float* rois      = (float*)d_out;                       // [B, 256, 5]
    float* scoresOut = rois + (size_t)BATCH * KMAX * 5;     // [B, 256]
    float* validOut  = scoresOut + (size_t)BATCH * KMAX;    // [B, 256]

    dim3 grid1(NBLKX, NBLKY, BATCH);
    score_nms_kernel<<<grid1, 256, 0, stream>>>(route, unc, top);

    tail_kernel<<<BATCH, TPB2, 0, stream>>>(top, scale, unc,
                                            imh, imw, rois, scoresOut, validOut);
}

// Round 17
// 70.543 us; speedup vs baseline: 1.5672x; 1.0464x over previous
//
#include <hip/hip_runtime.h>
#include <cstdint>
#include <cstddef>

#define BATCH 32
#define IMH 512
#define IMW 512
#define KMAX 256

// K1: register rolling-window NMS. Wave = 256 cols (4/lane), RPW output rows.
#define RPW 8
#define NBLKX 2
#define NBLKY 16
#define NBLK (NBLKX * NBLKY)   // 32 blocks/image
#define WCAP 512               // per-wave candidate cap (worst-case strict maxima in 256x8)

#define TPB2 512               // tail threads (8 waves)

typedef unsigned long long u64;

__device__ __forceinline__ float sigmoidf_(float x) {
    return 1.0f / (1.0f + expf(-x));
}
__device__ __forceinline__ float scoref_(float r, float u) {
    const float sg = sigmoidf_(r);
    return sg * sg * (1.0f - 0.35f * sigmoidf_(u));
}

// ---------------------------------------------------------------------------
// Register-resident wave-level bitonic sort, NO arrays (named scalars only, so
// SROA cannot demote to scratch — rule #20). Element e = r*64 + lane over
// regs v0..v3 (N=256). Shuffle phases via __shfl_xor; r-strides via reg swaps.
// ---------------------------------------------------------------------------
#define SHF(v, jj, dm) do {                                         \
    const u64 o_ = __shfl_xor((v), (jj), 64);                       \
    const bool km_ = (((lane & (jj)) == 0) == (dm));                \
    const u64 mn_ = ((v) < o_) ? (v) : o_;                          \
    const u64 mx_ = ((v) < o_) ? o_ : (v);                          \
    (v) = km_ ? mx_ : mn_;                                          \
} while (0)

#define RMAX(a, b) do {                                             \
    const u64 hi_ = ((a) > (b)) ? (a) : (b);                        \
    const u64 lo_ = ((a) > (b)) ? (b) : (a);                        \
    (a) = hi_; (b) = lo_;                                           \
} while (0)

#define RMIN(a, b) do {                                             \
    const u64 hi_ = ((a) > (b)) ? (a) : (b);                        \
    const u64 lo_ = ((a) > (b)) ? (b) : (a);                        \
    (a) = lo_; (b) = hi_;                                           \
} while (0)

// bitonic clean, N=256, descending (j = 128, 64 reg phases; 32..1 shuffles)
__device__ __forceinline__ void clean256(u64& v0, u64& v1, u64& v2, u64& v3,
                                         const int lane) {
    RMAX(v0, v2); RMAX(v1, v3);      // j=128: partner r^2
    RMAX(v0, v1); RMAX(v2, v3);      // j=64 : partner r^1
    #pragma unroll
    for (int j = 32; j > 0; j >>= 1) {
        SHF(v0, j, true); SHF(v1, j, true); SHF(v2, j, true); SHF(v3, j, true);
    }
}

// full bitonic sort, N=256, descending
__device__ __forceinline__ void sort256(u64& v0, u64& v1, u64& v2, u64& v3,
                                        const int lane) {
    #pragma unroll
    for (int k = 2; k <= 32; k <<= 1) {          // e&k == lane&k (k < 64)
        #pragma unroll
        for (int j = k >> 1; j > 0; j >>= 1) {
            const bool dm = ((lane & k) == 0);
            SHF(v0, j, dm); SHF(v1, j, dm); SHF(v2, j, dm); SHF(v3, j, dm);
        }
    }
    // k=64: dir = ((e&64)==0) = (r even)
    #pragma unroll
    for (int j = 32; j > 0; j >>= 1) {
        SHF(v0, j, true); SHF(v1, j, false); SHF(v2, j, true); SHF(v3, j, false);
    }
    // k=128: j=64 reg phase (pairs (0,1),(2,3); dir by r&2), then shuffles
    RMAX(v0, v1); RMIN(v2, v3);
    #pragma unroll
    for (int j = 32; j > 0; j >>= 1) {
        SHF(v0, j, true); SHF(v1, j, true); SHF(v2, j, false); SHF(v3, j, false);
    }
    // k=256 == clean
    clean256(v0, v1, v2, v3, lane);
}

// top-256 merge of two sorted-desc 256-lists: v = sorted top-256 of A∪B
__device__ __forceinline__ void merge256(u64& v0, u64& v1, u64& v2, u64& v3,
                                         u64 w0, u64 w1, u64 w2, u64 w3,
                                         const int lane) {
    const int rl = 63 ^ lane;                    // reverse lane
    const u64 b0 = __shfl(w3, rl, 64);           // B[255 - (0*64+lane)]
    const u64 b1 = __shfl(w2, rl, 64);
    const u64 b2 = __shfl(w1, rl, 64);
    const u64 b3 = __shfl(w0, rl, 64);
    v0 = (v0 > b0) ? v0 : b0;
    v1 = (v1 > b1) ? v1 : b1;
    v2 = (v2 > b2) ? v2 : b2;
    v3 = (v3 > b3) ? v3 : b3;
    clean256(v0, v1, v2, v3, lane);
}

// ---------------------------------------------------------------------------
// K1: fused score + 3x3 NMS (register rolling window). Wave-private LDS
// append region (register counter + ballot prefix, no atomics), register
// bitonic sort of the wave's candidates (256 fast path; 512 via two sorts +
// register merge), then 2 register-merge rounds across waves (4 barriers)
// produce the block's sorted top-256. Tournament property: any global top-256
// key is in its block's top-256.
// key = (score_bits<<32) | ~idx -> unsigned desc == (score desc, idx asc),
// matching lax.top_k's stable tie-break.
// ---------------------------------------------------------------------------
__global__ __launch_bounds__(256)
void score_nms_kernel(const float* __restrict__ route,
                      const float* __restrict__ unc,
                      u64* __restrict__ top) {
    const int b    = blockIdx.z;
    const int tid  = threadIdx.x;
    const int w    = tid >> 6;
    const int lane = tid & 63;
    const int y0   = (blockIdx.y * 4 + w) * RPW;
    const int x0   = blockIdx.x * 256 + lane * 4;
    const int blk  = blockIdx.y * NBLKX + blockIdx.x;

    __shared__ u64 lcand[4 * WCAP];      // 16 KB, per-wave regions
    u64* myR = lcand + w * WCAP;

    const float* rB = route + (size_t)b * IMH * IMW;
    const float* uB = unc   + (size_t)b * IMH * IMW;

    int ex = -1;
    if (lane == 0)       ex = x0 - 1;
    else if (lane == 63) ex = x0 + 4;
    const bool eAct = (ex >= 0 && ex < IMW);

    const u64 laneMaskLt = (1ull << lane) - 1ull;
    int wcnt = 0;                        // wave-uniform candidate count

    float sP[4], hP1[4], hP2[4];
    #pragma unroll
    for (int j = 0; j < 4; ++j) { sP[j] = -INFINITY; hP1[j] = -INFINITY; hP2[j] = -INFINITY; }

    const int ylast = y0 + RPW;
    bool v = (y0 - 1 >= 0);
    float4 r4, u4; float er = 0.f, eu = 0.f;
    if (v) {
        r4 = *(const float4*)(rB + (size_t)(y0 - 1) * IMW + x0);
        u4 = *(const float4*)(uB + (size_t)(y0 - 1) * IMW + x0);
        if (eAct) { er = rB[(size_t)(y0 - 1) * IMW + ex]; eu = uB[(size_t)(y0 - 1) * IMW + ex]; }
    }

    for (int y = y0 - 1; y <= ylast; ++y) {
        const int yn = y + 1;
        const bool vn = (yn <= ylast) && (yn < IMH);
        float4 r4n, u4n; float ern = 0.f, eun = 0.f;
        if (vn) {
            r4n = *(const float4*)(rB + (size_t)yn * IMW + x0);
            u4n = *(const float4*)(uB + (size_t)yn * IMW + x0);
            if (eAct) { ern = rB[(size_t)yn * IMW + ex]; eun = uB[(size_t)yn * IMW + ex]; }
        }

        float sC[4], hmC[4];
        float es = -INFINITY;
        if (v && eAct) es = scoref_(er, eu);
        if (v) {
            sC[0] = scoref_(r4.x, u4.x);
            sC[1] = scoref_(r4.y, u4.y);
            sC[2] = scoref_(r4.z, u4.z);
            sC[3] = scoref_(r4.w, u4.w);
        } else {
            sC[0] = sC[1] = sC[2] = sC[3] = -INFINITY;
        }
        float lft = __shfl_up(sC[3], 1, 64);
        if (lane == 0) lft = es;
        float rgt = __shfl_down(sC[0], 1, 64);
        if (lane == 63) rgt = es;
        if (v) {
            hmC[0] = fmaxf(fmaxf(lft,   sC[0]), sC[1]);
            hmC[1] = fmaxf(fmaxf(sC[0], sC[1]), sC[2]);
            hmC[2] = fmaxf(fmaxf(sC[1], sC[2]), sC[3]);
            hmC[3] = fmaxf(fmaxf(sC[2], sC[3]), rgt);
        } else {
            hmC[0] = hmC[1] = hmC[2] = hmC[3] = -INFINITY;
        }

        if (y >= y0 + 1) {
            const int yo = y - 1;
            bool p[4]; int cntT = 0;
            #pragma unroll
            for (int j = 0; j < 4; ++j) {
                const float m9 = fmaxf(fmaxf(hP2[j], hP1[j]), hmC[j]);
                p[j] = (sP[j] >= m9);
                cntT += p[j] ? 1 : 0;
            }
            const u64 B0 = __ballot(cntT & 1);
            const u64 B1 = __ballot(cntT & 2);
            const u64 B2 = __ballot(cntT & 4);
            const int total = __popcll(B0) + 2 * __popcll(B1) + 4 * __popcll(B2);
            if (total > 0) {
                const int prefix = __popcll(B0 & laneMaskLt) + 2 * __popcll(B1 & laneMaskLt)
                                 + 4 * __popcll(B2 & laneMaskLt);
                int mb = wcnt + prefix;
                #pragma unroll
                for (int j = 0; j < 4; ++j) {
                    if (p[j]) {
                        const unsigned idx = (unsigned)(yo * IMW + (x0 + j));
                        const u64 key = ((u64)__float_as_uint(sP[j]) << 32) | (unsigned)(~idx);
                        if (mb < WCAP) myR[mb] = key;
                        ++mb;
                    }
                }
                wcnt += total;
            }
        }

        #pragma unroll
        for (int j = 0; j < 4; ++j) { hP2[j] = hP1[j]; hP1[j] = hmC[j]; sP[j] = sC[j]; }
        r4 = r4n; u4 = u4n; er = ern; eu = eun; v = vn;
    }

    __syncthreads();    // appends visible before sort loads

    // ---- per-wave: register sort of the wave's candidates ----
    {
        const int m = (wcnt < WCAP) ? wcnt : WCAP;
        u64 v0, v1, v2, v3;
        v0 = (lane       < m) ? myR[lane]       : 0ull;
        v1 = (lane + 64  < m) ? myR[lane + 64]  : 0ull;
        v2 = (lane + 128 < m) ? myR[lane + 128] : 0ull;
        v3 = (lane + 192 < m) ? myR[lane + 192] : 0ull;
        sort256(v0, v1, v2, v3, lane);
        if (m > 256) {
            u64 w0, w1, w2, w3;
            w0 = (lane + 256 < m) ? myR[lane + 256] : 0ull;
            w1 = (lane + 320 < m) ? myR[lane + 320] : 0ull;
            w2 = (lane + 384 < m) ? myR[lane + 384] : 0ull;
            w3 = (lane + 448 < m) ? myR[lane + 448] : 0ull;
            sort256(w0, w1, w2, w3, lane);
            merge256(v0, v1, v2, v3, w0, w1, w2, w3, lane);
        }
        myR[lane]       = v0;
        myR[lane + 64]  = v1;
        myR[lane + 128] = v2;
        myR[lane + 192] = v3;
    }
    __syncthreads();

    // ---- round 1: waves 0,2 register-merge list pairs (0,1) and (2,3) ----
    if ((w & 1) == 0) {
        u64* A  = lcand + w * WCAP;
        u64* Bp = lcand + (w + 1) * WCAP;
        u64 v0 = A[lane],        v1 = A[lane + 64],  v2 = A[lane + 128], v3 = A[lane + 192];
        u64 w0 = Bp[lane],       w1 = Bp[lane + 64], w2 = Bp[lane + 128], w3 = Bp[lane + 192];
        merge256(v0, v1, v2, v3, w0, w1, w2, w3, lane);
        A[lane] = v0; A[lane + 64] = v1; A[lane + 128] = v2; A[lane + 192] = v3;
    }
    __syncthreads();

    // ---- round 2: wave 0 register-merges lists 0 and 2 ----
    if (w == 0) {
        u64* A  = lcand;
        u64* Bp = lcand + 2 * WCAP;
        u64 v0 = A[lane],        v1 = A[lane + 64],  v2 = A[lane + 128], v3 = A[lane + 192];
        u64 w0 = Bp[lane],       w1 = Bp[lane + 64], w2 = Bp[lane + 128], w3 = Bp[lane + 192];
        merge256(v0, v1, v2, v3, w0, w1, w2, w3, lane);
        A[lane] = v0; A[lane + 64] = v1; A[lane + 128] = v2; A[lane + 192] = v3;
    }
    __syncthreads();

    // flush the block's sorted top-256 (fixed segment, no counts)
    top[((size_t)b * NBLK + blk) * KMAX + tid] = lcand[tid];
}

// ---------------------------------------------------------------------------
// K2 (tail): 1 block/image x 512 threads. 32 sorted-desc 256-lists ->
// 5 rounds of pairwise top-256 merge (D[i] = max(A[i], B[255-i]) + 8-phase
// bitonic clean). Final list = exact sorted global top-256 -> ROI epilogue.
// ---------------------------------------------------------------------------
__global__ __launch_bounds__(TPB2)
void tail_kernel(const u64* __restrict__ top,
                 const float* __restrict__ scale,
                 const float* __restrict__ unc,
                 const int* __restrict__ imh,
                 const int* __restrict__ imw,
                 float* __restrict__ rois,
                 float* __restrict__ scoresOut,
                 float* __restrict__ validOut) {
    const int b   = blockIdx.x;
    const int tid = threadIdx.x;

    __shared__ u64 bufA[NBLK * KMAX];        // 64 KB
    __shared__ u64 bufB[(NBLK / 2) * KMAX];  // 32 KB

    const u64* tb = top + (size_t)b * NBLK * KMAX;
    for (int i = tid; i < NBLK * KMAX; i += TPB2) bufA[i] = tb[i];
    __syncthreads();

    u64* src = bufA;
    u64* dst = bufB;
    int nl = NBLK;
    while (nl > 1) {
        const int half = nl >> 1;
        const int E = half * KMAX;
        for (int p = tid; p < E; p += TPB2) {
            const int h = p >> 8;
            const int i = p & (KMAX - 1);
            const u64 a = src[(2 * h) * KMAX + i];
            const u64 c = src[(2 * h + 1) * KMAX + (KMAX - 1 - i)];
            dst[p] = (a > c) ? a : c;
        }
        __syncthreads();
        for (int j = KMAX >> 1; j > 0; j >>= 1) {
            for (int p = tid; p < (E >> 1); p += TPB2) {
                const int i   = ((p & ~(j - 1)) << 1) | (p & (j - 1));
                const int ixj = i | j;
                const u64 a = dst[i];
                const u64 c = dst[ixj];
                if (a < c) { dst[i] = c; dst[ixj] = a; }
            }
            __syncthreads();
        }
        u64* t = src; src = dst; dst = t;
        nl = half;
    }

    if (tid < KMAX) {
        const u64 k = src[tid];
        const float value = __uint_as_float((unsigned)(k >> 32));
        const bool valid  = (k != 0ull) && (value > 0.0f);

        float r0 = 0.f, r1 = 0.f, r2 = 0.f, r3 = 0.f, r4 = 0.f, sv = 0.f, vv = 0.f;
        if (valid) {
            const unsigned idx = ~(unsigned)(k & 0xFFFFFFFFull);
            const int y = (int)(idx / IMW);
            const int x = (int)(idx % IMW);
            const float cx = ((float)x + 0.5f) * 4.0f;
            const float cy = ((float)y + 0.5f) * 4.0f;
            const float sg = scale[(size_t)b * IMH * IMW + idx];
            const float uu = unc[(size_t)b * IMH * IMW + idx];
            const float su = sigmoidf_(uu);
            float side = 32.0f + sigmoidf_(sg) * (512.0f - 32.0f);
            side = side * (1.0f + 0.25f * su);
            const float half2 = side * 0.5f;
            const float fw = (float)imw[0];
            const float fh = (float)imh[0];
            r0 = (float)b;
            r1 = fminf(fmaxf(cx - half2, 0.0f), fw - 1.0f);
            r2 = fminf(fmaxf(cy - half2, 0.0f), fh - 1.0f);
            r3 = fminf(fmaxf(cx + half2, 1.0f), fw);
            r4 = fminf(fmaxf(cy + half2, 1.0f), fh);
            sv = value;
            vv = 1.0f;
        }
        float* roiP = rois + ((size_t)b * KMAX + tid) * 5;
        roiP[0] = r0; roiP[1] = r1; roiP[2] = r2; roiP[3] = r3; roiP[4] = r4;
        scoresOut[b * KMAX + tid] = sv;
        validOut[b * KMAX + tid]  = vv;
    }
}

extern "C" void kernel_launch(void* const* d_in, const int* in_sizes, int n_in,
                              void* d_out, int out_size, void* d_ws, size_t ws_size,
                              hipStream_t stream) {
    const float* route = (const float*)d_in[0];
    const float* scale = (const float*)d_in[1];
    const float* unc   = (const float*)d_in[2];
    const int*   imh   = (const int*)d_in[3];
    const int*   imw   = (const int*)d_in[4];

    // ws layout: [top B*NBLK*256 u64] = 2 MB
    u64* top = (u64*)d_ws;

    float* rois      = (float*)d_out;                       // [B, 256, 5]
    float* scoresOut = rois + (size_t)BATCH * KMAX * 5;     // [B, 256]
    float* validOut  = scoresOut + (size_t)BATCH * KMAX;    // [B, 256]

    dim3 grid1(NBLKX, NBLKY, BATCH);
    score_nms_kernel<<<grid1, 256, 0, stream>>>(route, unc, top);

    tail_kernel<<<BATCH, TPB2, 0, stream>>>(top, scale, unc,
                                            imh, imw, rois, scoresOut, validOut);
}